// Round 8
// baseline (209.129 us; speedup 1.0000x reference)
//
#include <hip/hip_runtime.h>
#include <cstdint>
#include <cstddef>

#define NE   384
#define NH   6
#define NKV  3
#define HD   64
#define BSZ  8
#define SEQ  2048
#define MROWS (BSZ*SEQ)
#define NT_Q (SEQ/64)      // 32 q-tiles

typedef __bf16 bf16x8 __attribute__((ext_vector_type(8)));
typedef __bf16 bf16x4 __attribute__((ext_vector_type(4)));
typedef float  f32x4  __attribute__((ext_vector_type(4)));
typedef unsigned short u16;
typedef u16 u16x8 __attribute__((ext_vector_type(8)));
typedef u16 u16x4 __attribute__((ext_vector_type(4)));

#define MFMA(a,b,c) __builtin_amdgcn_mfma_f32_16x16x32_bf16((a),(b),(c),0,0,0)
// Q pre-scale: log2(e)/sqrt(384) — softmax done base-2 (v_exp_f32 is 2^x)
#define QSCALE (1.4426950408889634f * 0.05103103630798288f)

// ---- swizzled LDS tiles, row stride 128 B (64 bf16): byte ^= (row&7)<<4
__device__ __forceinline__ bf16x8 ld_frag(const u16* lds, int row, int kk) {
    unsigned off = (unsigned)(row*128 + ((kk*2) ^ ((row&7)<<4)));
    return *reinterpret_cast<const bf16x8*>(reinterpret_cast<const char*>(lds) + off);
}
__device__ __forceinline__ void st_frag(u16* lds, int row, int kk, u16x8 v) {
    unsigned off = (unsigned)(row*128 + ((kk*2) ^ ((row&7)<<4)));
    *reinterpret_cast<u16x8*>(reinterpret_cast<char*>(lds) + off) = v;
}
// ---- A tile for projections: 32 rows x 384 cols bf16, row stride 768 B
__device__ __forceinline__ bf16x8 ldA(const u16* lds, int row, int kk) {
    unsigned off = (unsigned)(row*768 + ((kk*2) ^ ((row&7)<<4)));
    return *reinterpret_cast<const bf16x8*>(reinterpret_cast<const char*>(lds) + off);
}
__device__ __forceinline__ void stA(u16* lds, int row, int kk, u16x8 v) {
    unsigned off = (unsigned)(row*768 + ((kk*2) ^ ((row&7)<<4)));
    *reinterpret_cast<u16x8*>(reinterpret_cast<char*>(lds) + off) = v;
}
// packed b64 store into a (row&7)-swizzled 128B-stride tile
__device__ __forceinline__ void st_b64(u16* lds, int row, int col, u16x4 v) {
    unsigned off = (unsigned)(row*128 + ((col*2) ^ ((row&7)<<4)));
    *reinterpret_cast<u16x4*>(reinterpret_cast<char*>(lds) + off) = v;
}
__device__ __forceinline__ u16x4 pack4(f32x4 v) {
    bf16x4 h;
    h[0] = (__bf16)v[0]; h[1] = (__bf16)v[1]; h[2] = (__bf16)v[2]; h[3] = (__bf16)v[3];
    return *reinterpret_cast<u16x4*>(&h);
}
__device__ __forceinline__ bf16x8 cvt8(float4 a, float4 b) {
    bf16x8 v;
    v[0] = (__bf16)a.x; v[1] = (__bf16)a.y; v[2] = (__bf16)a.z; v[3] = (__bf16)a.w;
    v[4] = (__bf16)b.x; v[5] = (__bf16)b.y; v[6] = (__bf16)b.z; v[7] = (__bf16)b.w;
    return v;
}

// ---------------------------------------------------------------------------
// Prep: fp32 -> bf16 for x only (weights converted in-kernel to registers).
// ---------------------------------------------------------------------------
__global__ __launch_bounds__(256) void prep_kernel(
    const float* __restrict__ x, __bf16* __restrict__ xb)
{
    const int n8 = MROWS*NE/8;
    for (int i = blockIdx.x*256 + threadIdx.x; i < n8; i += gridDim.x*256) {
        float4 a = reinterpret_cast<const float4*>(x)[2*i];
        float4 b = reinterpret_cast<const float4*>(x)[2*i+1];
        reinterpret_cast<bf16x8*>(xb)[i] = cvt8(a, b);
    }
}

// ---------------------------------------------------------------------------
// QKV projection, register-resident weights (T14-style A prefetch).
// Block: 4 waves, 128 output cols (wave owns 32), 128 rows (4 m-tiles of 32).
// Wave loads its 32x384 W strip to 24 bf16x8 regs ONCE (fp32->bf16 on load),
// then the m-loop stages only A (24KB dbuf). 24 ds_read + 48 MFMA per m-tile.
// Strips: y=0..2 -> Q cols, y=3..5 -> K (384..575) / V (576..767) cols.
// Q written pre-scaled; V written transposed [B,KV,D,T].
// ---------------------------------------------------------------------------
__global__ __launch_bounds__(256) void qkv_proj_kernel(
    const __bf16* __restrict__ xb,
    const float* __restrict__ Wq, const float* __restrict__ Wk,
    const float* __restrict__ Wv,
    const float* __restrict__ bq, const float* __restrict__ bk,
    const float* __restrict__ bv,
    __bf16* __restrict__ Qb, __bf16* __restrict__ Kb, __bf16* __restrict__ Vt)
{
    __shared__ __align__(16) u16 Abuf[2][32*384];   // 2 x 24 KB

    const int tid = threadIdx.x;
    const int w  = tid >> 6, l = tid & 63;
    const int lr = l & 15, lg = l >> 4;
    const int m0 = blockIdx.x * 128;
    const int n0 = blockIdx.y * 128;
    const int arow = tid >> 3, ak = tid & 7;        // A staging coords

    // W strip -> registers (once per block), fp32 -> bf16
    bf16x8 wreg[2][12];
    float  wbias[2];
    #pragma unroll
    for (int nt = 0; nt < 2; ++nt) {
        int gc = n0 + w*32 + nt*16 + lr;
        const float* Wrow; float bb;
        if (gc < 384)      { Wrow = Wq + (size_t)gc*NE;       bb = bq[gc];     }
        else if (gc < 576) { Wrow = Wk + (size_t)(gc-384)*NE; bb = bk[gc-384]; }
        else               { Wrow = Wv + (size_t)(gc-576)*NE; bb = bv[gc-576]; }
        wbias[nt] = bb;
        #pragma unroll
        for (int ks = 0; ks < 12; ++ks) {
            float4 f0 = *reinterpret_cast<const float4*>(Wrow + ks*32 + lg*8);
            float4 f1 = *reinterpret_cast<const float4*>(Wrow + ks*32 + lg*8 + 4);
            wreg[nt][ks] = cvt8(f0, f1);
        }
    }

    // stage m-tile 0
    #pragma unroll
    for (int j = 0; j < 6; ++j)
        stA(Abuf[0], arow, (ak + j*8)*8,
            *reinterpret_cast<const u16x8*>(&xb[(size_t)(m0 + arow)*NE + (ak + j*8)*8]));
    __syncthreads();

    int cur = 0;
    #pragma unroll
    for (int mt = 0; mt < 4; ++mt) {
        // issue next tile's loads before compute (latency hides under MFMA)
        u16x8 pref[6];
        if (mt < 3) {
            #pragma unroll
            for (int j = 0; j < 6; ++j)
                pref[j] = *reinterpret_cast<const u16x8*>(
                    &xb[(size_t)(m0 + (mt+1)*32 + arow)*NE + (ak + j*8)*8]);
        }

        f32x4 acc[2][2];
        #pragma unroll
        for (int mf = 0; mf < 2; ++mf)
            #pragma unroll
            for (int nt = 0; nt < 2; ++nt) acc[mf][nt] = (f32x4)(0.0f);

        #pragma unroll
        for (int ks = 0; ks < 12; ++ks) {
            bf16x8 a0 = ldA(Abuf[cur], lr,      ks*32 + lg*8);
            bf16x8 a1 = ldA(Abuf[cur], 16 + lr, ks*32 + lg*8);
            acc[0][0] = MFMA(a0, wreg[0][ks], acc[0][0]);
            acc[0][1] = MFMA(a0, wreg[1][ks], acc[0][1]);
            acc[1][0] = MFMA(a1, wreg[0][ks], acc[1][0]);
            acc[1][1] = MFMA(a1, wreg[1][ks], acc[1][1]);
        }

        if (mt < 3) {
            #pragma unroll
            for (int j = 0; j < 6; ++j)
                stA(Abuf[cur ^ 1], arow, (ak + j*8)*8, pref[j]);
        }

        // epilogue stores for this m-tile
        #pragma unroll
        for (int nt = 0; nt < 2; ++nt) {
            int gc = n0 + w*32 + nt*16 + lr;
            float bb = wbias[nt];
            #pragma unroll
            for (int mf = 0; mf < 2; ++mf) {
                int m = m0 + mt*32 + mf*16 + lg*4;
                int b8 = m >> 11, t0 = m & 2047;
                if (gc < 384) {
                    int hh = gc >> 6, dd = gc & 63;
                    #pragma unroll
                    for (int r = 0; r < 4; ++r)
                        Qb[(((size_t)b8*NH + hh)*SEQ + t0 + r)*HD + dd] =
                            (__bf16)((acc[mf][nt][r] + bb) * QSCALE);
                } else if (gc < 576) {
                    int c = gc - 384, hh = c >> 6, dd = c & 63;
                    #pragma unroll
                    for (int r = 0; r < 4; ++r)
                        Kb[(((size_t)b8*NKV + hh)*SEQ + t0 + r)*HD + dd] =
                            (__bf16)(acc[mf][nt][r] + bb);
                } else {
                    int c = gc - 576, hh = c >> 6, dd = c & 63;
                    f32x4 v;
                    #pragma unroll
                    for (int r = 0; r < 4; ++r) v[r] = acc[mf][nt][r] + bb;
                    *reinterpret_cast<u16x4*>(
                        &Vt[(((size_t)b8*NKV + hh)*HD + dd)*SEQ + t0]) = pack4(v);
                }
            }
        }
        __syncthreads();
        cur ^= 1;
    }
}

// ---------------------------------------------------------------------------
// Flash attention, swapped-operand lane-local softmax (unchanged from r7).
// ---------------------------------------------------------------------------
__global__ __launch_bounds__(256) void attn_kernel(
    const __bf16* __restrict__ Qb, const __bf16* __restrict__ Kb,
    const __bf16* __restrict__ Vt, __bf16* __restrict__ Ab)
{
    __shared__ __align__(16) u16 Kbuf[2][64*64];
    __shared__ __align__(16) u16 Vbuf[2][64*64];
    __shared__ __align__(16) u16 Ps[4][16*64];     // 40 KB total

    const int tid = threadIdx.x;
    const int w  = tid >> 6, l = tid & 63;
    const int lr = l & 15, lg = l >> 4;
    const int p = blockIdx.x, h = blockIdx.y, b = blockIdx.z;
    const int kvh = h >> 1;                        // interleaved repeat_kv

    const __bf16* Kbase = Kb + ((size_t)b*NKV + kvh)*SEQ*HD;
    const __bf16* Vbase = Vt + ((size_t)b*NKV + kvh)*HD*SEQ;   // [D][T]

    const int srow = tid >> 3, sc8 = tid & 7;      // staging coords (K/V alike)

    bf16x8 ones;
    #pragma unroll
    for (int j = 0; j < 8; ++j) ones[j] = (__bf16)1.0f;

    for (int pass = 0; pass < 2; ++pass) {
        const int qtile = pass ? (NT_Q-1-p) : p;
        const int qt0 = qtile * 64;
        const __bf16* Qbase = Qb + (((size_t)b*NH + h)*SEQ + qt0)*HD;

        const __bf16* qrow = Qbase + (size_t)(w*16 + lr)*HD + lg*8;
        bf16x8 qf0 = *reinterpret_cast<const bf16x8*>(qrow);
        bf16x8 qf1 = *reinterpret_cast<const bf16x8*>(qrow + 32);

        st_frag(Kbuf[0], srow, sc8*8, *reinterpret_cast<const u16x8*>(&Kbase[(size_t)srow*HD + sc8*8]));
        st_frag(Kbuf[0], srow+32, sc8*8, *reinterpret_cast<const u16x8*>(&Kbase[(size_t)(srow+32)*HD + sc8*8]));
        st_frag(Vbuf[0], srow, sc8*8, *reinterpret_cast<const u16x8*>(&Vbase[(size_t)srow*SEQ + sc8*8]));
        st_frag(Vbuf[0], srow+32, sc8*8, *reinterpret_cast<const u16x8*>(&Vbase[(size_t)(srow+32)*SEQ + sc8*8]));
        __syncthreads();

        f32x4 oT[4];
        #pragma unroll
        for (int nt = 0; nt < 4; ++nt) oT[nt] = (f32x4)(0.0f);
        float mrun = -1e30f, lrun = 0.0f;
        const int q_abs = qt0 + w*16 + lr;

        int cur = 0;
        for (int jt = 0; jt <= qtile; ++jt) {
            const bool pre = (jt < qtile);
            u16x8 kpre0, kpre1, vpre0, vpre1;
            if (pre) {
                const int jn = (jt+1)*64;
                kpre0 = *reinterpret_cast<const u16x8*>(&Kbase[(size_t)(jn+srow)*HD + sc8*8]);
                kpre1 = *reinterpret_cast<const u16x8*>(&Kbase[(size_t)(jn+srow+32)*HD + sc8*8]);
                vpre0 = *reinterpret_cast<const u16x8*>(&Vbase[(size_t)srow*SEQ + jn + sc8*8]);
                vpre1 = *reinterpret_cast<const u16x8*>(&Vbase[(size_t)(srow+32)*SEQ + jn + sc8*8]);
            }

            const u16* Kc = Kbuf[cur];
            const u16* Vc = Vbuf[cur];

            f32x4 sT[4];
            #pragma unroll
            for (int nt = 0; nt < 4; ++nt) sT[nt] = (f32x4)(0.0f);
            #pragma unroll
            for (int nt = 0; nt < 4; ++nt) {
                sT[nt] = MFMA(ld_frag(Kc, nt*16 + lr, lg*8), qf0, sT[nt]);
                sT[nt] = MFMA(ld_frag(Kc, nt*16 + lr, 32 + lg*8), qf1, sT[nt]);
            }
            if (jt == qtile) {
                const int j0 = jt*64;
                #pragma unroll
                for (int nt = 0; nt < 4; ++nt)
                    #pragma unroll
                    for (int r = 0; r < 4; ++r)
                        if (j0 + nt*16 + lg*4 + r > q_abs) sT[nt][r] = -1e30f;
            }

            float mxa = fmaxf(fmaxf(sT[0][0], sT[0][1]), fmaxf(sT[0][2], sT[0][3]));
            float mxb = fmaxf(fmaxf(sT[1][0], sT[1][1]), fmaxf(sT[1][2], sT[1][3]));
            float mxc = fmaxf(fmaxf(sT[2][0], sT[2][1]), fmaxf(sT[2][2], sT[2][3]));
            float mxd = fmaxf(fmaxf(sT[3][0], sT[3][1]), fmaxf(sT[3][2], sT[3][3]));
            float mx = fmaxf(fmaxf(mxa, mxb), fmaxf(mxc, mxd));
            mx = fmaxf(mx, __shfl_xor(mx, 16));
            mx = fmaxf(mx, __shfl_xor(mx, 32));

            if (!__all(mx - mrun <= 8.0f)) {
                float mnew = fmaxf(mrun, mx);
                float corr = exp2f(mrun - mnew);
                mrun = mnew;
                lrun *= corr;
                #pragma unroll
                for (int nt = 0; nt < 4; ++nt)
                    #pragma unroll
                    for (int r = 0; r < 4; ++r) oT[nt][r] *= corr;
            }

            u16* P = Ps[w];
            #pragma unroll
            for (int nt = 0; nt < 4; ++nt) {
                f32x4 pv;
                #pragma unroll
                for (int r = 0; r < 4; ++r) pv[r] = exp2f(sT[nt][r] - mrun);
                st_b64(P, lr, nt*16 + lg*4, pack4(pv));
            }

            f32x4 rsacc = (f32x4)(0.0f);
            #pragma unroll
            for (int ks = 0; ks < 2; ++ks) {
                bf16x8 pf = ld_frag(P, lr, ks*32 + lg*8);
                rsacc = MFMA(ones, pf, rsacc);
                #pragma unroll
                for (int nt = 0; nt < 4; ++nt)
                    oT[nt] = MFMA(ld_frag(Vc, nt*16 + lr, ks*32 + lg*8), pf, oT[nt]);
            }
            lrun += rsacc[0];

            if (pre) {
                u16* Kd = Kbuf[cur ^ 1];
                u16* Vd = Vbuf[cur ^ 1];
                st_frag(Kd, srow,    sc8*8, kpre0);
                st_frag(Kd, srow+32, sc8*8, kpre1);
                st_frag(Vd, srow,    sc8*8, vpre0);
                st_frag(Vd, srow+32, sc8*8, vpre1);
            }
            __syncthreads();
            cur ^= 1;
        }

        float inv = 1.0f / lrun;
        int t = qt0 + w*16 + lr;
        size_t base = ((size_t)b*SEQ + t)*NE + h*HD;
        #pragma unroll
        for (int nt = 0; nt < 4; ++nt) {
            f32x4 v;
            #pragma unroll
            for (int r = 0; r < 4; ++r) v[r] = oT[nt][r] * inv;
            *reinterpret_cast<u16x4*>(&Ab[base + nt*16 + lg*4]) = pack4(v);
        }
    }
}

// ---------------------------------------------------------------------------
// Output projection, register-resident Wo. Same structure as qkv_proj.
// ---------------------------------------------------------------------------
__global__ __launch_bounds__(256) void out_proj_kernel(
    const __bf16* __restrict__ Ab, const float* __restrict__ Wo,
    const float* __restrict__ bo, float* __restrict__ out)
{
    __shared__ __align__(16) u16 Abuf[2][32*384];

    const int tid = threadIdx.x;
    const int w  = tid >> 6, l = tid & 63;
    const int lr = l & 15, lg = l >> 4;
    const int m0 = blockIdx.x * 128;
    const int n0 = blockIdx.y * 128;
    const int arow = tid >> 3, ak = tid & 7;

    bf16x8 wreg[2][12];
    float  wbias[2];
    #pragma unroll
    for (int nt = 0; nt < 2; ++nt) {
        int gc = n0 + w*32 + nt*16 + lr;
        const float* Wrow = Wo + (size_t)gc*NE;
        wbias[nt] = bo[gc];
        #pragma unroll
        for (int ks = 0; ks < 12; ++ks) {
            float4 f0 = *reinterpret_cast<const float4*>(Wrow + ks*32 + lg*8);
            float4 f1 = *reinterpret_cast<const float4*>(Wrow + ks*32 + lg*8 + 4);
            wreg[nt][ks] = cvt8(f0, f1);
        }
    }

    #pragma unroll
    for (int j = 0; j < 6; ++j)
        stA(Abuf[0], arow, (ak + j*8)*8,
            *reinterpret_cast<const u16x8*>(&Ab[(size_t)(m0 + arow)*NE + (ak + j*8)*8]));
    __syncthreads();

    int cur = 0;
    #pragma unroll
    for (int mt = 0; mt < 4; ++mt) {
        u16x8 pref[6];
        if (mt < 3) {
            #pragma unroll
            for (int j = 0; j < 6; ++j)
                pref[j] = *reinterpret_cast<const u16x8*>(
                    &Ab[(size_t)(m0 + (mt+1)*32 + arow)*NE + (ak + j*8)*8]);
        }

        f32x4 acc[2][2];
        #pragma unroll
        for (int mf = 0; mf < 2; ++mf)
            #pragma unroll
            for (int nt = 0; nt < 2; ++nt) acc[mf][nt] = (f32x4)(0.0f);

        #pragma unroll
        for (int ks = 0; ks < 12; ++ks) {
            bf16x8 a0 = ldA(Abuf[cur], lr,      ks*32 + lg*8);
            bf16x8 a1 = ldA(Abuf[cur], 16 + lr, ks*32 + lg*8);
            acc[0][0] = MFMA(a0, wreg[0][ks], acc[0][0]);
            acc[0][1] = MFMA(a0, wreg[1][ks], acc[0][1]);
            acc[1][0] = MFMA(a1, wreg[0][ks], acc[1][0]);
            acc[1][1] = MFMA(a1, wreg[1][ks], acc[1][1]);
        }

        if (mt < 3) {
            #pragma unroll
            for (int j = 0; j < 6; ++j)
                stA(Abuf[cur ^ 1], arow, (ak + j*8)*8, pref[j]);
        }

        #pragma unroll
        for (int nt = 0; nt < 2; ++nt) {
            int gc = n0 + w*32 + nt*16 + lr;
            float bb = wbias[nt];
            #pragma unroll
            for (int mf = 0; mf < 2; ++mf) {
                int m = m0 + mt*32 + mf*16 + lg*4;
                #pragma unroll
                for (int r = 0; r < 4; ++r)
                    out[(size_t)(m + r)*NE + gc] = acc[mf][nt][r] + bb;
            }
        }
        __syncthreads();
        cur ^= 1;
    }
}

extern "C" void kernel_launch(void* const* d_in, const int* in_sizes, int n_in,
                              void* d_out, int out_size, void* d_ws, size_t ws_size,
                              hipStream_t stream)
{
    const float* x  = (const float*)d_in[0];
    // d_in[1] = attn_mask (tril) — causal structure known; unused.
    const float* Wq = (const float*)d_in[2];
    const float* bq = (const float*)d_in[3];
    const float* Wk = (const float*)d_in[4];
    const float* bk = (const float*)d_in[5];
    const float* Wv = (const float*)d_in[6];
    const float* bv = (const float*)d_in[7];
    const float* Wo = (const float*)d_in[8];
    const float* bo = (const float*)d_in[9];
    float* out = (float*)d_out;

    // ws layout (bf16 elements)
    __bf16* xb  = (__bf16*)d_ws;                 // MROWS*NE
    __bf16* Qb  = xb + (size_t)MROWS*NE;         // [B,NH,T,D], pre-scaled
    __bf16* Kb  = Qb + (size_t)BSZ*NH*SEQ*HD;    // [B,KV,T,D]
    __bf16* Vt  = Kb + (size_t)BSZ*NKV*SEQ*HD;   // [B,KV,D,T] (transposed)
    __bf16* Ab  = xb;                            // alias: xb dead after qkv

    prep_kernel<<<1024, 256, 0, stream>>>(x, xb);
    qkv_proj_kernel<<<dim3(MROWS/128, 6), 256, 0, stream>>>(
        xb, Wq, Wk, Wv, bq, bk, bv, Qb, Kb, Vt);
    attn_kernel<<<dim3(NT_Q/2, NH, BSZ), 256, 0, stream>>>(Qb, Kb, Vt, Ab);
    out_proj_kernel<<<dim3(MROWS/128, 3), 256, 0, stream>>>(Ab, Wo, bo, out);
}